// Round 6
// baseline (245.031 us; speedup 1.0000x reference)
//
#include <hip/hip_runtime.h>

// PCEN: M_t = (1-s) M_{t-1} + s x_t (IIR along T, T=2048 contiguous per row),
// out = (x*(eps+M)^-alpha + bias)^power - bias^power.
//
// v6: compiler-proof streaming pipeline.
// Evidence from v2/v3/v5: VGPR_Count 28-32 despite 8-16 float4 "in flight" ->
// the compiler sank/re-issued the loads (legal: const+restrict, re-reads hit
// L2), de-pipelining every source-level prefetch. Result: each wave bursts
// loads, drains vmcnt to 0 (whole-row scan needs all chunks), then computes
// ~thousands of cycles with ZERO memory ops outstanding -> chip-wide memory
// duty cycle ~35% -> the invariant 80us / 2.5 TB/s wall. fillBuffer sustains
// 6.7 TB/s at 9% occupancy because its waves never stop issuing.
//
// Fix: per-wave private LDS double-buffer fed by global_load_lds (a
// SIDE-EFFECTING intrinsic: cannot be sunk, duplicated, or rematerialized)
// with hand-counted inline-asm vmcnt waits (never 0 in the loop), no
// __syncthreads anywhere (each wave owns its LDS slice). Per row:
//   wait vmcnt(counted) -> ds_read_b128 x8 -> lgkmcnt(0) ->
//   issue row i+2 into the just-freed buffer -> compute -> store.
// Next-row loads stay outstanding through the ENTIRE compute+store window;
// depth-2 buffering gives >= 1 full iteration of latency slack.
// vmcnt ledger (8 loads L / 8 stores S per row, in-order retirement):
//   prologue L0,L1 (16 out). i=0: wait 8 (L0 done). body: issue L2, stores S0.
//   i>=1 top, newest-after-L_i = {L_{i+1}, S_{i-1}} = 16 -> wait vmcnt(16)
//   (also covers the tail rows, where no new L is issued).
// LDS 64KB/block (4 waves x 2 x 8KB) -> 2 blocks/CU, 8 waves/CU; grid = 512
// blocks = exactly 2/CU. Duty cycle, not occupancy, is the lever here.

#define T_LEN  2048
#define NCH    8             // chunks per row
#define CHUNK  256           // elems per chunk = 64 lanes * 4
#define RPW    8             // rows per wave
#define ROWB   T_LEN         // floats per LDS row buffer
#define WSLICE (2 * T_LEN)   // per-wave LDS floats (double buffer)

__device__ __forceinline__ float fast_exp2(float x) { return __builtin_amdgcn_exp2f(x); }
__device__ __forceinline__ float fast_log2(float x) { return __builtin_amdgcn_logf(x); }
__device__ __forceinline__ float readlane63(float v) {
    return __int_as_float(__builtin_amdgcn_readlane(__float_as_int(v), 63));
}

__global__ __launch_bounds__(256, 2) void pcen_kernel(
    const float* __restrict__ x,
    const float* __restrict__ alpha_p,
    const float* __restrict__ power_p,
    const float* __restrict__ bias_p,
    float* __restrict__ out)
{
    __shared__ float lds[4 * WSLICE];   // 64 KB/block, 16 KB per wave

    const int wave = threadIdx.x >> 6;
    const int lane = threadIdx.x & 63;
    const int gw   = (blockIdx.x << 2) | wave;

    float* const lbase = &lds[wave * WSLICE];

    const float alpha = alpha_p[0];
    const float power = power_p[0];
    const float bias  = bias_p[0];

    const float A  = 0.985f;   // 1 - SMOOTH
    const float S  = 0.015f;   // SMOOTH
    const float A2 = A * A;
    const float f4 = A2 * A2;  // A^4: per-segment decay

    const float* const xw = x   + (size_t)gw * (RPW * T_LEN);
    float*       const ow = out + (size_t)gw * (RPW * T_LEN) + 4 * lane;

    // f^lane = A^(4*lane) via 6 select-muls; afterwards t = A^256.
    float fl = 1.0f, t = f4;
#pragma unroll
    for (int b = 1; b < 64; b <<= 1) { fl = (lane & b) ? fl * t : fl; t *= t; }
    const float F = t;         // A^256: whole-chunk decay

    const float bias_pow = fast_exp2(power * fast_log2(bias));
    const float nalpha   = -alpha;

    // Async row stage: row i -> buffer b. Global src per-lane (16B/lane,
    // contiguous 1KB per issue); LDS dest wave-uniform base + lane*16 ->
    // row lands LINEARLY in the buffer (elem e at float offset e).
#define ISSUE_ROW(i, b)                                                         \
    {                                                                           \
        const float* gp = xw + (size_t)(i) * T_LEN + 4 * lane;                  \
        float* lp = lbase + (b) * ROWB;                                         \
        _Pragma("unroll")                                                       \
        for (int c = 0; c < NCH; ++c) {                                         \
            __builtin_amdgcn_global_load_lds(                                   \
                (const __attribute__((address_space(1))) void*)(gp + c * CHUNK),\
                (__attribute__((address_space(3))) void*)(lp + c * CHUNK),      \
                16, 0, 0);                                                      \
        }                                                                       \
    }

    // ---- prologue: fill both buffers ----
    ISSUE_ROW(0, 0);
    ISSUE_ROW(1, 1);

#pragma unroll 1
    for (int i = 0; i < RPW; ++i) {
        const int cur = i & 1;

        // counted wait: buffer[cur]'s 8 loads retired; newer ops stay in flight
        if (i == 0) asm volatile("s_waitcnt vmcnt(8)" ::: "memory");
        else        asm volatile("s_waitcnt vmcnt(16)" ::: "memory");

        // LDS -> regs: 8 x ds_read_b128 at 16B/lane stride (conflict-free)
        float4 v[NCH];
        const float* lb = lbase + cur * ROWB + 4 * lane;
#pragma unroll
        for (int c = 0; c < NCH; ++c)
            v[c] = *reinterpret_cast<const float4*>(lb + c * CHUNK);

        // all ds_reads retired -> safe to overwrite this buffer with row i+2;
        // those loads then cover the whole compute+store window below.
        asm volatile("s_waitcnt lgkmcnt(0)" ::: "memory");
        if (i + 2 < RPW) ISSUE_ROW(i + 2, cur);

        // ---- lane-local carry-free segment scans (4-deep per chunk) ----
        float s[NCH];
#pragma unroll
        for (int c = 0; c < NCH; ++c) {
            float m = 0.0f;
            m = fmaf(A, m, S * v[c].x);
            m = fmaf(A, m, S * v[c].y);
            m = fmaf(A, m, S * v[c].z);
            m = fmaf(A, m, S * v[c].w);
            s[c] = m;
        }

        // ---- Kogge-Stone: 6 steps, 8 independent shuffles per step ----
        {
            float g = f4;
#pragma unroll
            for (int d = 1; d < 64; d <<= 1) {
#pragma unroll
                for (int c = 0; c < NCH; ++c) {
                    const float so = __shfl_up(s[c], d, 64);
                    if (lane >= d) s[c] = fmaf(g, so, s[c]);
                }
                g *= g;
            }
        }

        // ---- carries + epilogue + coalesced stores ----
        float R = 0.0f;        // abs M at end of previous chunk (uniform)
#pragma unroll
        for (int c = 0; c < NCH; ++c) {
            float e = __shfl_up(s[c], 1, 64);
            if (lane == 0) e = 0.0f;
            const float s63 = readlane63(s[c]);
            float M = fmaf(fl, R, e);     // abs M before this lane's elem 0
            R = fmaf(F, R, s63);          // advance uniform chunk carry

            float4 r;
#pragma unroll
            for (int j = 0; j < 4; ++j) {
                const float xj = (j == 0) ? v[c].x : (j == 1) ? v[c].y
                               : (j == 2) ? v[c].z : v[c].w;
                M = fmaf(A, M, S * xj);
                const float den = 1e-9f + M;
                const float tt  = fmaf(xj, fast_exp2(nalpha * fast_log2(den)), bias);
                const float rr  = fast_exp2(power * fast_log2(tt)) - bias_pow;
                if (j == 0) r.x = rr; else if (j == 1) r.y = rr;
                else if (j == 2) r.z = rr; else r.w = rr;
            }
            *reinterpret_cast<float4*>(ow + (size_t)i * T_LEN + c * CHUNK) = r;
        }
    }
#undef ISSUE_ROW
}

extern "C" void kernel_launch(void* const* d_in, const int* in_sizes, int n_in,
                              void* d_out, int out_size, void* d_ws, size_t ws_size,
                              hipStream_t stream) {
    const float* x       = (const float*)d_in[0];
    const float* alpha_p = (const float*)d_in[1];
    const float* power_p = (const float*)d_in[2];
    const float* bias_p  = (const float*)d_in[3];
    float* out           = (float*)d_out;

    const int nrows  = in_sizes[0] / T_LEN;       // 16384
    const int blocks = nrows / (4 * RPW);         // 512 = exactly 2 per CU

    pcen_kernel<<<blocks, 256, 0, stream>>>(x, alpha_p, power_p, bias_p, out);
}

// Round 7
// 232.789 us; speedup vs baseline: 1.0526x; 1.0526x over previous
//
#include <hip/hip_runtime.h>

// PCEN: M_t = (1-s) M_{t-1} + s x_t (IIR along T, T=2048 contiguous per row),
// out = (x*(eps+M)^-alpha + bias)^power - bias^power.
//
// v7: v3 body (best measured: 80.0us) at ONE WAVE PER BLOCK (block=64,
// grid=16384). Last untried occupancy-independent axis: dispatch shape.
// All prior versions used 256-thread blocks whose 4 waves launch/retire in
// lockstep on one CU; single-wave blocks let the CP fill CUs fluidly and
// decouple wave lifetimes. Everything else is the proven v3 structure:
//  - lane owns 4 CONTIGUOUS elems per 256-elem chunk -> every global
//    load/store instr is a contiguous 1KB wave access (16 lines, optimal);
//  - 8 upfront loads; carry-free Kogge-Stone over segment end-states
//    (factor A^4), 8 chunks interleaved per step;
//  - inter-chunk carry = scalar recurrence R <- s63 + A^256*R, applied
//    per-lane via precomputed A^(4*lane).
// Zero LDS, zero barriers, ~32 VGPR.
//
// Evidence ledger (6 kernels, 80-87us): time invariant under occupancy
// 17-65%, VGPR 28-88, coalescing, barriers, prefetch depth, forced-async
// LDS pipeline (v6). FETCH bit-identical 64MiB+eps (= half the input; in+out
// exactly fill the 256MiB L3), WRITE exactly 128MiB, DRAM 2.4-2.5 TB/s.
// Pre-committed: if v7 is also ~80us, the wall is the memory system's
// service rate for this fixed mixed stream -> declare effective roofline.

#define T_LEN 2048
#define NCH   8            // chunks per row
#define CHUNK 256          // elems per chunk = 64 lanes * 4

__device__ __forceinline__ float fast_exp2(float x) { return __builtin_amdgcn_exp2f(x); }
__device__ __forceinline__ float fast_log2(float x) { return __builtin_amdgcn_logf(x); }
__device__ __forceinline__ float readlane63(float v) {
    return __int_as_float(__builtin_amdgcn_readlane(__float_as_int(v), 63));
}

__global__ __launch_bounds__(64, 8) void pcen_kernel(
    const float* __restrict__ x,
    const float* __restrict__ alpha_p,
    const float* __restrict__ power_p,
    const float* __restrict__ bias_p,
    float* __restrict__ out)
{
    const int lane = threadIdx.x;          // block == one wave
    const int row  = blockIdx.x;

    const float alpha = alpha_p[0];
    const float power = power_p[0];
    const float bias  = bias_p[0];

    const float A  = 0.985f;   // 1 - SMOOTH
    const float S  = 0.015f;   // SMOOTH
    const float A2 = A * A;
    const float f4 = A2 * A2;  // A^4: per-segment decay

    const float* xr  = x   + (size_t)row * T_LEN + 4 * lane;
    float*       orw = out + (size_t)row * T_LEN + 4 * lane;

    // ---- issue ALL chunk loads upfront (8 x contiguous 1KB wave-loads) ----
    float4 v[NCH];
#pragma unroll
    for (int c = 0; c < NCH; ++c)
        v[c] = *reinterpret_cast<const float4*>(xr + c * CHUNK);

    // ---- f^lane = A^(4*lane) via 6 select-muls; afterwards t = A^256 ----
    float fl = 1.0f, t = f4;
#pragma unroll
    for (int b = 1; b < 64; b <<= 1) {
        fl = (lane & b) ? fl * t : fl;
        t *= t;
    }
    const float F = t;         // A^256: whole-chunk decay

    // ---- lane-local scans (carry-free): segment end-state per chunk ----
    float s[NCH];
#pragma unroll
    for (int c = 0; c < NCH; ++c) {
        float m = 0.0f;
        m = fmaf(A, m, S * v[c].x);
        m = fmaf(A, m, S * v[c].y);
        m = fmaf(A, m, S * v[c].z);
        m = fmaf(A, m, S * v[c].w);
        s[c] = m;
    }

    // ---- Kogge-Stone inclusive scans, 8 chunks interleaved per step ----
    {
        float g = f4;
#pragma unroll
        for (int d = 1; d < 64; d <<= 1) {
#pragma unroll
            for (int c = 0; c < NCH; ++c) {
                const float so = __shfl_up(s[c], d, 64);
                if (lane >= d) s[c] = fmaf(g, so, s[c]);
            }
            g *= g;
        }
    }

    const float bias_pow = fast_exp2(power * fast_log2(bias));
    const float nalpha   = -alpha;

    // ---- carries + epilogue + coalesced stores, chunk by chunk ----
    float R = 0.0f;            // abs M at end of previous chunk (uniform)
#pragma unroll
    for (int c = 0; c < NCH; ++c) {
        float e = __shfl_up(s[c], 1, 64);
        if (lane == 0) e = 0.0f;
        const float s63 = readlane63(s[c]);
        float M = fmaf(fl, R, e);      // abs M before this lane's elem 0
        R = fmaf(F, R, s63);           // advance uniform chunk carry

        float4 r;
#pragma unroll
        for (int j = 0; j < 4; ++j) {
            const float xj = (j == 0) ? v[c].x : (j == 1) ? v[c].y
                           : (j == 2) ? v[c].z : v[c].w;
            M = fmaf(A, M, S * xj);
            const float den = 1e-9f + M;
            const float tt  = fmaf(xj, fast_exp2(nalpha * fast_log2(den)), bias);
            const float rr  = fast_exp2(power * fast_log2(tt)) - bias_pow;
            if (j == 0) r.x = rr; else if (j == 1) r.y = rr;
            else if (j == 2) r.z = rr; else r.w = rr;
        }
        *reinterpret_cast<float4*>(orw + c * CHUNK) = r;   // contiguous 1KB
    }
}

extern "C" void kernel_launch(void* const* d_in, const int* in_sizes, int n_in,
                              void* d_out, int out_size, void* d_ws, size_t ws_size,
                              hipStream_t stream) {
    const float* x       = (const float*)d_in[0];
    const float* alpha_p = (const float*)d_in[1];
    const float* power_p = (const float*)d_in[2];
    const float* bias_p  = (const float*)d_in[3];
    float* out           = (float*)d_out;

    const int nrows = in_sizes[0] / T_LEN;    // 16384 rows = 16384 blocks
    pcen_kernel<<<nrows, 64, 0, stream>>>(x, alpha_p, power_p, bias_p, out);
}